// Round 1
// baseline (354.292 us; speedup 1.0000x reference)
//
#include <hip/hip_runtime.h>
#include <stdint.h>
#include <math.h>

#define NUM_ANCHORS 5
#define NUM_CLASSES 80
#define MAX_BOXES   50

// Workspace layout:
//   ws[0] : float   sum of p over masked cells
//   ws[1] : uint32  count of masked cells
//   ws[2] : int32   max p as float bits (init 0xFF800000 = -inf)
//   bytes 16.. : uint8 mask[cells]

__global__ void zero_ws(uint32_t* ws, int n_words) {
    int i = blockIdx.x * blockDim.x + threadIdx.x;
    if (i < n_words) ws[i] = 0u;
}

__global__ void build_mask(const float* __restrict__ target,
                           uint8_t* __restrict__ mask,
                           int* __restrict__ hdr,
                           int nB, int nH, int nW) {
#pragma clang fp contract(off)
    int b = threadIdx.x;
    if (b == 0) hdr[2] = (int)0xFF800000;  // -inf bits for max accumulator
    if (b >= nB) return;
    const float aw[NUM_ANCHORS] = {0.57273f, 1.87446f, 3.33843f, 7.88282f, 9.77052f};
    const float ah[NUM_ANCHORS] = {0.677385f, 2.06253f, 5.47434f, 3.52778f, 9.16828f};
    const float* t = target + (long)b * MAX_BOXES * 5;
    for (int i = 0; i < MAX_BOXES; ++i) {
        float x = t[i * 5 + 1];
        if (x == 0.0f) break;  // valid = cumprod(x != 0)
        float gx = x * (float)nW;
        float gy = t[i * 5 + 2] * (float)nH;
        float gw = t[i * 5 + 3] * (float)nW;
        float gh = t[i * 5 + 4] * (float)nH;
        int gi = (int)floorf(gx); gi = min(max(gi, 0), nW - 1);
        int gj = (int)floorf(gy); gj = min(max(gj, 0), nH - 1);
        // first-max-wins argmax over IoU of (gw,gh) vs anchors
        int best = 0; float bestiou = -1.0f;
        for (int n = 0; n < NUM_ANCHORS; ++n) {
            float inter = fminf(gw, aw[n]) * fminf(gh, ah[n]);
            float uni   = gw * gh + aw[n] * ah[n] - inter;
            float iou   = inter / uni;
            if (iou > bestiou) { bestiou = iou; best = n; }
        }
        long flat = (((long)b * NUM_ANCHORS + best) * nH + gj) * nW + gi;
        mask[flat] = 1;
    }
}

__global__ void __launch_bounds__(256)
reduce_cells(const float* __restrict__ output,
             const uint8_t* __restrict__ mask,
             float* __restrict__ sumf,
             unsigned* __restrict__ cnt,
             int* __restrict__ maxbits,
             const int* __restrict__ reqd,
             int nH, int nW, long cells) {
    int lane = threadIdx.x & 63;
    int wave = threadIdx.x >> 6;
    long chunk = (long)blockIdx.x * 4 + wave;  // 64 cells per wave
    long base  = chunk * 64;
    if (base >= cells) return;
    uint8_t m = (base + lane < cells) ? mask[base + lane] : (uint8_t)0;
    unsigned long long bal = __ballot(m != 0);
    if (bal == 0) return;
    const int HW = nH * nW;
    const int rq = *reqd;
    while (bal) {
        int bit = __ffsll((unsigned long long)bal) - 1;
        bal &= bal - 1;
        long cell = base + bit;
        int ba = (int)(cell / HW);   // b*NUM_ANCHORS + a
        int hw = (int)(cell % HW);   // gj*nW + gi
        // logit channel for class k is ba*85 + 5 + k
        const float* ptr = output + ((long)(ba * (5 + NUM_CLASSES) + 5)) * HW + hw;
        float v0 = ptr[(long)lane * HW];
        float v1 = (lane < NUM_CLASSES - 64) ? ptr[(long)(lane + 64) * HW] : -INFINITY;
        float mx = fmaxf(v0, v1);
        #pragma unroll
        for (int off = 32; off; off >>= 1) mx = fmaxf(mx, __shfl_xor(mx, off, 64));
        float e0 = expf(v0 - mx);
        float e1 = (lane < NUM_CLASSES - 64) ? expf(v1 - mx) : 0.0f;
        float s = e0 + e1;
        #pragma unroll
        for (int off = 32; off; off >>= 1) s += __shfl_xor(s, off, 64);
        float lr = (rq < 64) ? __shfl(v0, rq, 64) : __shfl(v1, rq - 64, 64);
        if (lane == 0) {
            float p = expf(lr - mx) / s;
            atomicAdd(sumf, p);
            atomicAdd(cnt, 1u);
            atomicMax(maxbits, __float_as_int(p));  // p > 0, int-order == float-order
        }
    }
}

__global__ void finalize(const float* __restrict__ sumf,
                         const unsigned* __restrict__ cnt,
                         const int* __restrict__ maxbits,
                         float* __restrict__ out) {
    out[0] = sumf[0] / (float)cnt[0];
    out[1] = __int_as_float(maxbits[0]);
}

extern "C" void kernel_launch(void* const* d_in, const int* in_sizes, int n_in,
                              void* d_out, int out_size, void* d_ws, size_t ws_size,
                              hipStream_t stream) {
    const float* output = (const float*)d_in[0];
    const float* target = (const float*)d_in[1];
    const int*   reqd   = (const int*)d_in[2];
    float* out = (float*)d_out;

    int nB = in_sizes[1] / (MAX_BOXES * 5);              // 64
    int HW = in_sizes[0] / (nB * (5 + NUM_CLASSES) * NUM_ANCHORS);  // 1444
    int nW = 1; while (nW * nW < HW) ++nW;               // 38 (square grid)
    int nH = HW / nW;                                    // 38
    long cells = (long)nB * NUM_ANCHORS * nH * nW;       // 461440

    float*    sumf    = (float*)d_ws;
    unsigned* cnt     = (unsigned*)d_ws + 1;
    int*      maxbits = (int*)d_ws + 2;
    uint8_t*  mask    = (uint8_t*)d_ws + 16;

    // zero header + mask (mask bytes, rounded up to words)
    int n_words = (int)((16 + cells + 3) / 4);
    zero_ws<<<(n_words + 255) / 256, 256, 0, stream>>>((uint32_t*)d_ws, n_words);

    build_mask<<<1, 64, 0, stream>>>(target, mask, (int*)d_ws, nB, nH, nW);

    long chunks = (cells + 63) / 64;
    int blocks = (int)((chunks + 3) / 4);
    reduce_cells<<<blocks, 256, 0, stream>>>(output, mask, sumf, cnt, maxbits,
                                             reqd, nH, nW, cells);

    finalize<<<1, 1, 0, stream>>>(sumf, cnt, maxbits, out);
}

// Round 2
// 213.792 us; speedup vs baseline: 1.6572x; 1.6572x over previous
//
#include <hip/hip_runtime.h>
#include <stdint.h>
#include <math.h>

#define NUM_ANCHORS 5
#define NUM_CLASSES 80
#define MAX_BOXES   50

// Workspace layout (uint32 words):
//   ws[0] : float   sum of p over masked cells
//   ws[1] : uint32  count of distinct masked cells (== list length)
//   ws[2] : int32   max p as float bits (init 0xFF800000 = -inf)
//   ws[3] : pad
//   ws[4 .. 4+listCap)            : int32 list of flat cell ids
//   ws[4+listCap .. +bmWords)     : dedup bit-array, 1 bit per cell

__global__ void init_ws(uint32_t* ws, int n_words) {
    int i = blockIdx.x * blockDim.x + threadIdx.x;
    if (i < n_words) ws[i] = (i == 2) ? 0xFF800000u : 0u;
}

// One block (one wave) per batch; one lane per GT box.
__global__ void build_list(const float* __restrict__ target,
                           uint32_t* __restrict__ hdr,
                           int* __restrict__ list,
                           uint32_t* __restrict__ bm,
                           int nH, int nW) {
#pragma clang fp contract(off)
    int b = blockIdx.x;
    int lane = threadIdx.x;
    const float* t = target + (long)b * MAX_BOXES * 5;
    float x = 1.0f, y = 0.0f, w = 0.0f, h = 0.0f;
    if (lane < MAX_BOXES) {
        x = t[lane * 5 + 1];
        y = t[lane * 5 + 2];
        w = t[lane * 5 + 3];
        h = t[lane * 5 + 4];
    }
    // valid = cumprod(x != 0): lanes strictly before the first zero box
    unsigned long long zb = __ballot(lane < MAX_BOXES && x == 0.0f);
    int first_zero = zb ? (__ffsll(zb) - 1) : MAX_BOXES;
    if (lane >= first_zero) return;

    float gx = x * (float)nW;
    float gy = y * (float)nH;
    float gw = w * (float)nW;
    float gh = h * (float)nH;
    int gi = min(max((int)floorf(gx), 0), nW - 1);
    int gj = min(max((int)floorf(gy), 0), nH - 1);

    const float aw[NUM_ANCHORS] = {0.57273f, 1.87446f, 3.33843f, 7.88282f, 9.77052f};
    const float ah[NUM_ANCHORS] = {0.677385f, 2.06253f, 5.47434f, 3.52778f, 9.16828f};
    int best = 0; float bestiou = -1.0f;
    #pragma unroll
    for (int n = 0; n < NUM_ANCHORS; ++n) {
        float inter = fminf(gw, aw[n]) * fminf(gh, ah[n]);
        float uni   = gw * gh + aw[n] * ah[n] - inter;
        float iou   = inter / uni;
        if (iou > bestiou) { bestiou = iou; best = n; }  // first-max-wins
    }
    int flat = ((b * NUM_ANCHORS + best) * nH + gj) * nW + gi;
    uint32_t bit = 1u << (flat & 31);
    uint32_t old = atomicOr(&bm[flat >> 5], bit);
    if (!(old & bit)) {
        int idx = (int)atomicAdd(&hdr[1], 1u);
        list[idx] = flat;
    }
}

// One wave per list entry: 80-class softmax, block-combined atomics.
__global__ void __launch_bounds__(256)
reduce_list(const float* __restrict__ output,
            const uint32_t* __restrict__ hdr,
            const int* __restrict__ list,
            float* __restrict__ sumf,
            int* __restrict__ maxbits,
            const int* __restrict__ reqd,
            int HW) {
    __shared__ float sp[4];
    __shared__ float sm[4];
    int lane = threadIdx.x & 63;
    int wave = threadIdx.x >> 6;
    int g = blockIdx.x * 4 + wave;
    int count = (int)hdr[1];
    float p = 0.0f, pm = -INFINITY;
    if (g < count) {
        int cell = list[g];
        int ba = cell / HW;          // b*NUM_ANCHORS + a
        int hw = cell - ba * HW;     // gj*nW + gi
        const float* ptr = output + ((long)(ba * (5 + NUM_CLASSES) + 5)) * HW + hw;
        float v0 = ptr[(long)lane * HW];
        float v1 = (lane < NUM_CLASSES - 64) ? ptr[(long)(lane + 64) * HW] : -INFINITY;
        float mx = fmaxf(v0, v1);
        #pragma unroll
        for (int off = 32; off; off >>= 1) mx = fmaxf(mx, __shfl_xor(mx, off, 64));
        float e0 = expf(v0 - mx);
        float e1 = (lane < NUM_CLASSES - 64) ? expf(v1 - mx) : 0.0f;
        float s = e0 + e1;
        #pragma unroll
        for (int off = 32; off; off >>= 1) s += __shfl_xor(s, off, 64);
        int rq = *reqd;
        float lr = (rq < 64) ? __shfl(v0, rq, 64) : __shfl(v1, rq - 64, 64);
        p = expf(lr - mx) / s;
        pm = p;
    }
    if (lane == 0) { sp[wave] = p; sm[wave] = pm; }
    __syncthreads();
    if (threadIdx.x == 0) {
        float ts = 0.0f, tm = -INFINITY;
        #pragma unroll
        for (int w = 0; w < 4; ++w) { ts += sp[w]; tm = fmaxf(tm, sm[w]); }
        if (tm > -INFINITY) {
            atomicAdd(sumf, ts);
            atomicMax(maxbits, __float_as_int(tm));  // p > 0: int order == float order
        }
    }
}

__global__ void finalize(const float* __restrict__ sumf,
                         const uint32_t* __restrict__ hdr,
                         const int* __restrict__ maxbits,
                         float* __restrict__ out) {
    out[0] = sumf[0] / (float)hdr[1];
    out[1] = __int_as_float(maxbits[0]);
}

extern "C" void kernel_launch(void* const* d_in, const int* in_sizes, int n_in,
                              void* d_out, int out_size, void* d_ws, size_t ws_size,
                              hipStream_t stream) {
    const float* output = (const float*)d_in[0];
    const float* target = (const float*)d_in[1];
    const int*   reqd   = (const int*)d_in[2];
    float* out = (float*)d_out;

    int nB = in_sizes[1] / (MAX_BOXES * 5);                           // 64
    int HW = in_sizes[0] / (nB * (5 + NUM_CLASSES) * NUM_ANCHORS);    // 1444
    int nW = 1; while (nW * nW < HW) ++nW;                            // 38
    int nH = HW / nW;                                                 // 38
    long cells = (long)nB * NUM_ANCHORS * nH * nW;                    // 461440

    int listCap = nB * MAX_BOXES;                                     // 3200
    int bmWords = (int)((cells + 31) / 32);                           // 14420
    int n_words = 4 + listCap + bmWords;                              // ~17.6K words

    uint32_t* ws   = (uint32_t*)d_ws;
    uint32_t* hdr  = ws;
    float*    sumf = (float*)ws;          // hdr[0]
    int*      maxb = (int*)(ws + 2);      // hdr[2]
    int*      list = (int*)(ws + 4);
    uint32_t* bm   = ws + 4 + listCap;

    init_ws<<<(n_words + 255) / 256, 256, 0, stream>>>(ws, n_words);

    build_list<<<nB, 64, 0, stream>>>(target, hdr, list, bm, nH, nW);

    int rblocks = (listCap + 3) / 4;  // 4 waves (entries) per 256-thread block
    reduce_list<<<rblocks, 256, 0, stream>>>(output, hdr, list, sumf, maxb,
                                             reqd, HW);

    finalize<<<1, 1, 0, stream>>>(sumf, hdr, maxb, out);
}